// Round 2
// baseline (187.945 us; speedup 1.0000x reference)
//
#include <hip/hip_runtime.h>
#include <math.h>

// Problem constants
constexpr int B = 2, C = 256, H = 56, W = 96;
constexpr int HW = H * W;
constexpr int RADIUS = 4;

// int8 quantization: scale 127/6 for both fmaps; dots rescaled at the end.
#define SQ 21.166666f                    // 127/6
constexpr float SCL = 36.0f / (127.0f * 127.0f * 16.0f);  // 1/(SQ^2 * sqrt(C))

// Workspace layout (byte offsets, all 16B-aligned)
constexpr size_t F1T_B = 0;                                   // i8 [B,HW,C]
constexpr size_t L0_B  = (size_t)B * HW * C;                  // i8 [B,HW,C]
constexpr size_t L1_B  = L0_B + (size_t)B * HW * C;           // i8 [B,28*48,C]
constexpr size_t L2_B  = L1_B + (size_t)B * 28 * 48 * C;      // i8 [B,14*24,C]
constexpr size_t L3_B  = L2_B + (size_t)B * 14 * 24 * C;      // i8 [B,7*12,C]
constexpr size_t OUT0_ELEMS = (size_t)B * 324 * HW;

static __device__ __forceinline__ int dot4acc(int a, int b, int c) {
#if __has_builtin(__builtin_amdgcn_sdot4)
    return __builtin_amdgcn_sdot4(a, b, c, false);
#else
    c += (int)(char)(a) * (int)(char)(b);
    c += (int)(char)(a >> 8) * (int)(char)(b >> 8);
    c += (int)(char)(a >> 16) * (int)(char)(b >> 16);
    c += (int)(char)(a >> 24) * (int)(char)(b >> 24);
    return c;
#endif
}

static __device__ __forceinline__ unsigned short pack_i8x2(float a, float b) {
    int ia = (int)rintf(a); ia = ia < -127 ? -127 : (ia > 127 ? 127 : ia);
    int ib = (int)rintf(b); ib = ib < -127 ? -127 : (ib > 127 ? 127 : ib);
    return (unsigned short)((ia & 0xFF) | ((ib & 0xFF) << 8));
}

// ---------------------------------------------------------------------------
// prep_kernel: fused
//   [0, TP_BLOCKS)                 : fp32->i8 channel-last transpose (fmap1/fmap2)
//   [TP_BLOCKS, +CU_BLOCKS)        : convex upsample (independent inputs)
//   [TP_BLOCKS+CU_BLOCKS, +PL)     : pyramid pools DIRECTLY from fp32 fmap2
//                                    (pooling commutes with the dot product;
//                                    single quantization -> more accurate)
constexpr int TP_BLOCKS = (HW / 32) * (C / 64) * 2 * B;   // 2688
constexpr int CU_BLOCKS = B * H * 8;                      // 896
constexpr int PL_BLOCKS = B * 7 * 12;                     // 168 (8x8 tiles)
__global__ __launch_bounds__(256) void prep_kernel(
    const float* __restrict__ fmap1, const float* __restrict__ fmap2,
    const float* __restrict__ flow, const float* __restrict__ mask,
    char* __restrict__ ws, float* __restrict__ out1) {
    __shared__ float smem[72 * 96 + 2 * 3 * 98];
    int bid = blockIdx.x;
    int tid = threadIdx.x;

    if (bid < TP_BLOCKS) {
        float (*tile)[33] = (float(*)[33])smem;   // 64 x 33 floats
        int zi = bid / 672;                       // 672 = 168*4
        int rem = bid % 672;
        int by = rem / 168, bx = rem % 168;
        int b = zi & 1, m = zi >> 1;              // m=0: fmap1, m=1: fmap2
        const float* src = m ? fmap2 : fmap1;
        unsigned short* dst = (unsigned short*)(ws + (m ? L0_B : F1T_B));
        int c0 = by * 64, q0 = bx * 32;
        int tx = tid & 31, ty = tid >> 5;
#pragma unroll
        for (int r = 0; r < 8; ++r) {
            int cl = ty + r * 8;
            tile[cl][tx] = src[((size_t)(b * C + c0 + cl)) * HW + q0 + tx];
        }
        __syncthreads();
#pragma unroll
        for (int r = 0; r < 4; ++r) {
            int pl = ty + r * 8;
            dst[((size_t)b * HW + q0 + pl) * 128 + (c0 >> 1) + tx] =
                pack_i8x2(tile[2 * tx][pl] * SQ, tile[2 * tx + 1][pl] * SQ);
        }
        return;
    }

    if (bid < TP_BLOCKS + CU_BLOCKS) {
        // ---- convex upsample ----
        float* msk = smem;               // 72*96
        float* fst = smem + 72 * 96;     // 2*3*98
        int cb = bid - TP_BLOCKS;
        int i = cb & 7;
        int r = cb >> 3;
        int h = r % H;
        int b = r / H;

        for (int idx = tid; idx < 72 * 96; idx += 256) {
            int row = idx / 96, wc = idx - row * 96;
            int k = row >> 3, j = row & 7;
            int gl = k * 64 + i * 8 + j;
            msk[idx] = mask[((size_t)(b * 576 + gl)) * HW + h * W + wc];
        }
        for (int idx = tid; idx < 588; idx += 256) {
            int ch = idx / 294;
            int rem2 = idx - ch * 294;
            int rr = rem2 / 98;
            int xw = rem2 - rr * 98;
            int hh = h + rr - 1, ww = xw - 1;
            float v = 0.f;
            if (hh >= 0 && hh < H && ww >= 0 && ww < W)
                v = 8.0f * flow[((size_t)(b * 2 + ch)) * HW + hh * W + ww];
            fst[idx] = v;
        }
        __syncthreads();

#pragma unroll
        for (int rr = 0; rr < 3; ++rr) {
            int col = tid + rr * 256;    // 0..767
            int w = col >> 3, j = col & 7;
            float m[9], mx = -1e30f;
#pragma unroll
            for (int k = 0; k < 9; ++k) {
                m[k] = msk[(k * 8 + j) * 96 + w];
                mx = fmaxf(mx, m[k]);
            }
            float sum = 0.f;
#pragma unroll
            for (int k = 0; k < 9; ++k) {
                m[k] = __expf(m[k] - mx);
                sum += m[k];
            }
            float inv = 1.0f / sum;
            float a0 = 0.f, a1 = 0.f;
#pragma unroll
            for (int k = 0; k < 9; ++k) {
                int ki = k / 3, kj = k - ki * 3;
                float wgt = m[k] * inv;
                a0 = fmaf(wgt, fst[0 * 294 + ki * 98 + w + kj], a0);
                a1 = fmaf(wgt, fst[1 * 294 + ki * 98 + w + kj], a1);
            }
            size_t row8 = (size_t)8 * h + i;
            out1[((size_t)(b * 2 + 0) * 448 + row8) * 768 + col] = a0;
            out1[((size_t)(b * 2 + 1) * 448 + row8) * 768 + col] = a1;
        }
        return;
    }

    // ---- pyramid pools from fp32 fmap2 ----
    // Block = one 8x8 spatial tile of one batch. Wave wv handles channel-pairs
    // j in [wv*32, wv*32+32). Lane (py,px) = (lane>>3, lane&7) holds one pixel;
    // butterfly shfl reductions give every lane its 2x2 / 4x4 / 8x8 group sum.
    {
        int pb = bid - TP_BLOCKS - CU_BLOCKS;      // 0..167
        int b = pb / 84;
        int t = pb % 84;
        int y3 = t / 12, x3 = t % 12;
        int wv = tid >> 6, lane = tid & 63;
        int py = lane >> 3, px = lane & 7;

        unsigned short* D1 = (unsigned short*)(ws + L1_B);
        unsigned short* D2 = (unsigned short*)(ws + L2_B);
        unsigned short* D3 = (unsigned short*)(ws + L3_B);
        const float* srcp = fmap2 + (size_t)b * C * HW + (size_t)(y3 * 8 + py) * W + x3 * 8 + px;

        for (int j = wv * 32; j < wv * 32 + 32; ++j) {
            float va = srcp[(size_t)(2 * j) * HW];
            float vb = srcp[(size_t)(2 * j + 1) * HW];
            float a1 = va + __shfl_xor(va, 1); a1 += __shfl_xor(a1, 8);
            float b1 = vb + __shfl_xor(vb, 1); b1 += __shfl_xor(b1, 8);
            float a2 = a1 + __shfl_xor(a1, 2); a2 += __shfl_xor(a2, 16);
            float b2 = b1 + __shfl_xor(b1, 2); b2 += __shfl_xor(b2, 16);
            float a3 = a2 + __shfl_xor(a2, 4); a3 += __shfl_xor(a3, 32);
            float b3 = b2 + __shfl_xor(b2, 4); b3 += __shfl_xor(b3, 32);
            if ((lane & 9) == 0) {                 // px,py even -> L1 writer
                int Y = y3 * 4 + (py >> 1), X = x3 * 4 + (px >> 1);
                D1[((size_t)(b * 28 + Y) * 48 + X) * 128 + j] =
                    pack_i8x2(a1 * 0.25f * SQ, b1 * 0.25f * SQ);
            }
            if ((lane & 27) == 0) {                // px,py %4==0 -> L2 writer
                int Y = y3 * 2 + (py >> 2), X = x3 * 2 + (px >> 2);
                D2[((size_t)(b * 14 + Y) * 24 + X) * 128 + j] =
                    pack_i8x2(a2 * 0.0625f * SQ, b2 * 0.0625f * SQ);
            }
            if (lane == 0) {
                D3[((size_t)(b * 7 + y3) * 12 + x3) * 128 + j] =
                    pack_i8x2(a3 * 0.015625f * SQ, b3 * 0.015625f * SQ);
            }
        }
    }
}

// ---------------------------------------------------------------------------
// corr_fused: 8 queries per block, 256 threads = 4 waves, wave = pyramid level.
// 4 lanes per position: each lane dots 64 contiguous channels (4x int4 A,
// 4x int4 column, 16 sdot4), 2 shfl_xor reduce. 16 positions/wave-iteration,
// 7 iterations per (query,level). All 4x8x100 corner dots staged in LDS,
// then bilinear combine + DIRECT [B,324,HW] f32 output.
__global__ __launch_bounds__(256, 5) void corr_fused(
    const float* __restrict__ coords, const char* __restrict__ ws,
    float* __restrict__ out0) {
    __shared__ float Dsh[4][8][101];   // stride 101: conflict-free reads
    __shared__ float Wxy[4][8][2];

    int tid = threadIdx.x;
    int l = tid >> 6;              // wave = level
    int lane = tid & 63;
    int v = lane & 3;              // channel quarter (64 ch)
    int grp = lane >> 2;           // position index within iteration, 0..15

    int g0 = blockIdx.x * 8;       // global flat query base
    int b = g0 / HW;
    int hw0 = g0 - b * HW;

    int Hl = H >> l, Wl = W >> l;
    size_t off = (l == 0 ? L0_B : (l == 1 ? L1_B : (l == 2 ? L2_B : L3_B)));
    const char* base8 = ws + off + (size_t)b * Hl * Wl * C;
    float scale = (l == 0 ? 1.0f : (l == 1 ? 0.5f : (l == 2 ? 0.25f : 0.125f)));

    // p = it*16 + grp; (xo,yo) = (p%10, p/10); advance p+=16: xo+=6 mod 10.
    int xo0 = grp < 10 ? grp : grp - 10;
    int yo0 = grp < 10 ? 0 : 1;

    const char* f1b = ws + F1T_B;

#pragma unroll 1
    for (int qi = 0; qi < 8; ++qi) {
        int g = g0 + qi;
        const int4* ap = (const int4*)(f1b + (size_t)g * C + (v << 6));
        int4 A0 = ap[0], A1 = ap[1], A2 = ap[2], A3 = ap[3];

        float cx = coords[(size_t)(b * 2 + 0) * HW + hw0 + qi];
        float cy = coords[(size_t)(b * 2 + 1) * HW + hw0 + qi];
        float fx = cx * scale, fy = cy * scale;
        float fxf = floorf(fx), fyf = floorf(fy);
        float wx = fx - fxf, wy = fy - fyf;
        int ix = (int)fxf, iy = (int)fyf;
        if (lane == 0) { Wxy[l][qi][0] = wx; Wxy[l][qi][1] = wy; }

        int xo = xo0, yo = yo0;
#pragma unroll
        for (int it = 0; it < 7; ++it) {
            bool live = (it < 6) | (grp < 4);      // p < 100
            int x = ix - RADIUS + xo;
            int y = iy - RADIUS + yo;
            int s0 = 0, s1 = 0, s2 = 0, s3 = 0;
            if (live && (unsigned)x < (unsigned)Wl && (unsigned)y < (unsigned)Hl) {
                const int4* cp = (const int4*)(base8 + ((y * Wl + x) << 8) + (v << 6));
                int4 c0 = cp[0], c1 = cp[1], c2 = cp[2], c3 = cp[3];
                s0 = dot4acc(c0.x, A0.x, s0); s1 = dot4acc(c0.y, A0.y, s1);
                s2 = dot4acc(c0.z, A0.z, s2); s3 = dot4acc(c0.w, A0.w, s3);
                s0 = dot4acc(c1.x, A1.x, s0); s1 = dot4acc(c1.y, A1.y, s1);
                s2 = dot4acc(c1.z, A1.z, s2); s3 = dot4acc(c1.w, A1.w, s3);
                s0 = dot4acc(c2.x, A2.x, s0); s1 = dot4acc(c2.y, A2.y, s1);
                s2 = dot4acc(c2.z, A2.z, s2); s3 = dot4acc(c2.w, A2.w, s3);
                s0 = dot4acc(c3.x, A3.x, s0); s1 = dot4acc(c3.y, A3.y, s1);
                s2 = dot4acc(c3.z, A3.z, s2); s3 = dot4acc(c3.w, A3.w, s3);
            }
            int s = (s0 + s1) + (s2 + s3);
            s += __shfl_xor(s, 1);
            s += __shfl_xor(s, 2);
            if (v == 0 && live) Dsh[l][qi][it * 16 + grp] = (float)s * SCL;
            xo += 6;
            int cr = xo >= 10;
            xo -= cr ? 10 : 0;
            yo += 1 + cr;
        }
    }
    __syncthreads();

    // Bilinear combine + direct [B,324,HW] f32 write (q fast -> 32B segments)
    for (int o = tid; o < 324 * 8; o += 256) {
        int q = o & 7, ch = o >> 3;
        int lv = ch / 81;
        int o81 = ch - lv * 81;
        int xo = o81 / 9;                      // x-offset slow (reference quirk)
        int yo = o81 - xo * 9;                 // y-offset fast
        float wxv = Wxy[lv][q][0], wyv = Wxy[lv][q][1];
        const float* D = Dsh[lv][q];
        float v00 = D[yo * 10 + xo];
        float v01 = D[yo * 10 + xo + 1];
        float v10 = D[yo * 10 + xo + 10];
        float v11 = D[yo * 10 + xo + 11];
        float res = (1.f - wyv) * ((1.f - wxv) * v00 + wxv * v01)
                  +        wyv  * ((1.f - wxv) * v10 + wxv * v11);
        out0[((size_t)(b * 324 + ch)) * HW + hw0 + q] = res;
    }
}

extern "C" void kernel_launch(void* const* d_in, const int* in_sizes, int n_in,
                              void* d_out, int out_size, void* d_ws, size_t ws_size,
                              hipStream_t stream) {
    const float* fmap1  = (const float*)d_in[0];
    const float* fmap2  = (const float*)d_in[1];
    const float* coords = (const float*)d_in[2];
    const float* flow   = (const float*)d_in[3];
    const float* maskp  = (const float*)d_in[4];
    float* out = (float*)d_out;
    char* ws = (char*)d_ws;

    prep_kernel<<<TP_BLOCKS + CU_BLOCKS + PL_BLOCKS, 256, 0, stream>>>(
        fmap1, fmap2, flow, maskp, ws, out + OUT0_ELEMS);
    corr_fused<<<B * HW / 8, 256, 0, stream>>>(coords, ws, out);
}

// Round 3
// 154.950 us; speedup vs baseline: 1.2129x; 1.2129x over previous
//
#include <hip/hip_runtime.h>
#include <math.h>

// Problem constants
constexpr int B = 2, C = 256, H = 56, W = 96;
constexpr int HW = H * W;
constexpr int RADIUS = 4;

// int8 quantization: scale 127/6 for both fmaps; dots rescaled at the end.
#define SQ 21.166666f                    // 127/6
constexpr float SCL = 36.0f / (127.0f * 127.0f * 16.0f);  // 1/(SQ^2 * sqrt(C))

// Workspace layout (byte offsets, all 16B-aligned)
constexpr size_t F1T_B = 0;                                   // i8 [B,HW,C]
constexpr size_t L0_B  = (size_t)B * HW * C;                  // i8 [B,HW,C]
constexpr size_t L1_B  = L0_B + (size_t)B * HW * C;           // i8 [B,28*48,C]
constexpr size_t L2_B  = L1_B + (size_t)B * 28 * 48 * C;      // i8 [B,14*24,C]
constexpr size_t L3_B  = L2_B + (size_t)B * 14 * 24 * C;      // i8 [B,7*12,C]
constexpr size_t OUT0_ELEMS = (size_t)B * 324 * HW;

static __device__ __forceinline__ int dot4acc(int a, int b, int c) {
#if __has_builtin(__builtin_amdgcn_sdot4)
    return __builtin_amdgcn_sdot4(a, b, c, false);
#else
    c += (int)(char)(a) * (int)(char)(b);
    c += (int)(char)(a >> 8) * (int)(char)(b >> 8);
    c += (int)(char)(a >> 16) * (int)(char)(b >> 16);
    c += (int)(char)(a >> 24) * (int)(char)(b >> 24);
    return c;
#endif
}

static __device__ __forceinline__ unsigned short pack_i8x2(float a, float b) {
    int ia = (int)rintf(a); ia = ia < -127 ? -127 : (ia > 127 ? 127 : ia);
    int ib = (int)rintf(b); ib = ib < -127 ? -127 : (ib > 127 ? 127 : ib);
    return (unsigned short)((ia & 0xFF) | ((ib & 0xFF) << 8));
}

// ---------------------------------------------------------------------------
// prep_kernel: fused {fp32->i8 channel-last transpose of fmap1/fmap2} and
// {convex upsample} (independent inputs).
constexpr int TP_BLOCKS = (HW / 32) * (C / 64) * 2 * B;   // 2688
constexpr int CU_BLOCKS = B * H * 8;                      // 896
__global__ __launch_bounds__(256) void prep_kernel(
    const float* __restrict__ fmap1, const float* __restrict__ fmap2,
    const float* __restrict__ flow, const float* __restrict__ mask,
    char* __restrict__ ws, float* __restrict__ out1) {
    __shared__ float smem[72 * 96 + 2 * 3 * 98];
    int bid = blockIdx.x;
    int tid = threadIdx.x;

    if (bid < TP_BLOCKS) {
        float (*tile)[33] = (float(*)[33])smem;   // 64 x 33 floats
        int zi = bid / 672;                       // 672 = 168*4
        int rem = bid % 672;
        int by = rem / 168, bx = rem % 168;
        int b = zi & 1, m = zi >> 1;              // m=0: fmap1, m=1: fmap2
        const float* src = m ? fmap2 : fmap1;
        unsigned short* dst = (unsigned short*)(ws + (m ? L0_B : F1T_B));
        int c0 = by * 64, q0 = bx * 32;
        int tx = tid & 31, ty = tid >> 5;
#pragma unroll
        for (int r = 0; r < 8; ++r) {
            int cl = ty + r * 8;
            tile[cl][tx] = src[((size_t)(b * C + c0 + cl)) * HW + q0 + tx];
        }
        __syncthreads();
#pragma unroll
        for (int r = 0; r < 4; ++r) {
            int pl = ty + r * 8;
            dst[((size_t)b * HW + q0 + pl) * 128 + (c0 >> 1) + tx] =
                pack_i8x2(tile[2 * tx][pl] * SQ, tile[2 * tx + 1][pl] * SQ);
        }
        return;
    }

    // ---- convex upsample ----
    float* msk = smem;               // 72*96
    float* fst = smem + 72 * 96;     // 2*3*98
    int cb = bid - TP_BLOCKS;
    int i = cb & 7;
    int r = cb >> 3;
    int h = r % H;
    int b = r / H;

    for (int idx = tid; idx < 72 * 96; idx += 256) {
        int row = idx / 96, wc = idx - row * 96;
        int k = row >> 3, j = row & 7;
        int gl = k * 64 + i * 8 + j;
        msk[idx] = mask[((size_t)(b * 576 + gl)) * HW + h * W + wc];
    }
    for (int idx = tid; idx < 588; idx += 256) {
        int ch = idx / 294;
        int rem2 = idx - ch * 294;
        int rr = rem2 / 98;
        int xw = rem2 - rr * 98;
        int hh = h + rr - 1, ww = xw - 1;
        float v = 0.f;
        if (hh >= 0 && hh < H && ww >= 0 && ww < W)
            v = 8.0f * flow[((size_t)(b * 2 + ch)) * HW + hh * W + ww];
        fst[idx] = v;
    }
    __syncthreads();

#pragma unroll
    for (int rr = 0; rr < 3; ++rr) {
        int col = tid + rr * 256;    // 0..767
        int w = col >> 3, j = col & 7;
        float m[9], mx = -1e30f;
#pragma unroll
        for (int k = 0; k < 9; ++k) {
            m[k] = msk[(k * 8 + j) * 96 + w];
            mx = fmaxf(mx, m[k]);
        }
        float sum = 0.f;
#pragma unroll
        for (int k = 0; k < 9; ++k) {
            m[k] = __expf(m[k] - mx);
            sum += m[k];
        }
        float inv = 1.0f / sum;
        float a0 = 0.f, a1 = 0.f;
#pragma unroll
        for (int k = 0; k < 9; ++k) {
            int ki = k / 3, kj = k - ki * 3;
            float wgt = m[k] * inv;
            a0 = fmaf(wgt, fst[0 * 294 + ki * 98 + w + kj], a0);
            a1 = fmaf(wgt, fst[1 * 294 + ki * 98 + w + kj], a1);
        }
        size_t row8 = (size_t)8 * h + i;
        out1[((size_t)(b * 2 + 0) * 448 + row8) * 768 + col] = a0;
        out1[((size_t)(b * 2 + 1) * 448 + row8) * 768 + col] = a1;
    }
}

// ---------------------------------------------------------------------------
// build_pools: pyramid levels 1..3 from i8 L0; one thread per channel PAIR.
constexpr int NP1 = B * 28 * 48 * C / 2;   // 344,064
constexpr int NP2 = B * 14 * 24 * C / 2;   //  86,016
constexpr int NP3 = B * 7 * 12 * C / 2;    //  21,504

template <int S>
static __device__ __forceinline__ void pool_accum(const unsigned short* src,
                                                  int& sx, int& sy) {
#pragma unroll
    for (int dy = 0; dy < S; ++dy)
#pragma unroll
        for (int dx = 0; dx < S; ++dx) {
            unsigned short v = src[(size_t)dy * (W * 128) + dx * 128];
            sx += (int)(char)(v & 0xFF);
            sy += (int)(char)(v >> 8);
        }
}

__global__ __launch_bounds__(256) void build_pools(char* __restrict__ ws) {
    const unsigned short* L0p = (const unsigned short*)(ws + L0_B);
    int t = blockIdx.x * 256 + threadIdx.x;
    int l, tl;
    if (t < NP1)             { l = 1; tl = t; }
    else if (t < NP1 + NP2)  { l = 2; tl = t - NP1; }
    else                     { l = 3; tl = t - NP1 - NP2; }
    int Wo = W >> l, Ho = H >> l, S = 1 << l;
    int c2 = tl & 127;
    int r = tl >> 7;
    int x = r % Wo; r /= Wo;
    int y = r % Ho;
    int b = r / Ho;
    const unsigned short* src =
        L0p + ((size_t)(b * H + y * S) * W + x * S) * 128 + c2;
    int sx = 0, sy = 0;
    if (l == 1)      pool_accum<2>(src, sx, sy);
    else if (l == 2) pool_accum<4>(src, sx, sy);
    else             pool_accum<8>(src, sx, sy);
    float inv = 1.0f / (S * S);
    unsigned short* dst = (unsigned short*)(ws + (l == 1 ? L1_B : (l == 2 ? L2_B : L3_B)));
    dst[tl] = pack_i8x2((float)sx * inv, (float)sy * inv);
}

// ---------------------------------------------------------------------------
// corr_fused: 4 queries per block (grid 2688), 256 threads = 4 waves,
// wave = pyramid level. 4 lanes per position; COALESCED chunk order:
// instruction k reads one 64-B line per position (lane v covers bytes
// k*64 + v*16). A-fragment partitioned identically (exact: dot is a sum
// over channels). 16 sdot4 + 2 shfl_xor per 16 positions, 7 iters/(q,l).
// Direct [B,324,HW] f32 output.
__global__ __launch_bounds__(256, 8) void corr_fused(
    const float* __restrict__ coords, const char* __restrict__ ws,
    float* __restrict__ out0) {
    __shared__ float Dsh[4][4][101];   // stride 101: conflict-free reads
    __shared__ float Wxy[4][4][2];

    int tid = threadIdx.x;
    int l = tid >> 6;              // wave = level
    int lane = tid & 63;
    int v = lane & 3;              // 16-B sub-chunk within each 64-B line
    int grp = lane >> 2;           // position index within iteration, 0..15

    int g0 = blockIdx.x * 4;       // global flat query base
    int b = g0 / HW;
    int hw0 = g0 - b * HW;

    int Hl = H >> l, Wl = W >> l;
    size_t off = (l == 0 ? L0_B : (l == 1 ? L1_B : (l == 2 ? L2_B : L3_B)));
    const char* base8 = ws + off + (size_t)b * Hl * Wl * C;
    float scale = (l == 0 ? 1.0f : (l == 1 ? 0.5f : (l == 2 ? 0.25f : 0.125f)));

    // p = it*16 + grp; (xo,yo) = (p%10, p/10); advance p+=16: xo+=6 mod 10.
    int xo0 = grp < 10 ? grp : grp - 10;
    int yo0 = grp < 10 ? 0 : 1;

    const char* f1b = ws + F1T_B;

#pragma unroll 1
    for (int qi = 0; qi < 4; ++qi) {
        int g = g0 + qi;
        // A chunks at k*64 + v*16 (match column partition)
        const char* ab = f1b + (size_t)g * C + (v << 4);
        int4 A0 = *(const int4*)(ab);
        int4 A1 = *(const int4*)(ab + 64);
        int4 A2 = *(const int4*)(ab + 128);
        int4 A3 = *(const int4*)(ab + 192);

        float cx = coords[(size_t)(b * 2 + 0) * HW + hw0 + qi];
        float cy = coords[(size_t)(b * 2 + 1) * HW + hw0 + qi];
        float fx = cx * scale, fy = cy * scale;
        float fxf = floorf(fx), fyf = floorf(fy);
        float wx = fx - fxf, wy = fy - fyf;
        int ix = (int)fxf, iy = (int)fyf;
        if (lane == 0) { Wxy[l][qi][0] = wx; Wxy[l][qi][1] = wy; }

        int xo = xo0, yo = yo0;
#pragma unroll
        for (int it = 0; it < 7; ++it) {
            bool live = (it < 6) | (grp < 4);      // p < 100
            int x = ix - RADIUS + xo;
            int y = iy - RADIUS + yo;
            int s0 = 0, s1 = 0, s2 = 0, s3 = 0;
            if (live && (unsigned)x < (unsigned)Wl && (unsigned)y < (unsigned)Hl) {
                // instruction k: 4 lanes cover one 64-B line of this position
                const char* rp = base8 + (((size_t)(y * Wl + x)) << 8) + (v << 4);
                int4 c0 = *(const int4*)(rp);
                int4 c1 = *(const int4*)(rp + 64);
                int4 c2 = *(const int4*)(rp + 128);
                int4 c3 = *(const int4*)(rp + 192);
                s0 = dot4acc(c0.x, A0.x, s0); s1 = dot4acc(c0.y, A0.y, s1);
                s2 = dot4acc(c0.z, A0.z, s2); s3 = dot4acc(c0.w, A0.w, s3);
                s0 = dot4acc(c1.x, A1.x, s0); s1 = dot4acc(c1.y, A1.y, s1);
                s2 = dot4acc(c1.z, A1.z, s2); s3 = dot4acc(c1.w, A1.w, s3);
                s0 = dot4acc(c2.x, A2.x, s0); s1 = dot4acc(c2.y, A2.y, s1);
                s2 = dot4acc(c2.z, A2.z, s2); s3 = dot4acc(c2.w, A2.w, s3);
                s0 = dot4acc(c3.x, A3.x, s0); s1 = dot4acc(c3.y, A3.y, s1);
                s2 = dot4acc(c3.z, A3.z, s2); s3 = dot4acc(c3.w, A3.w, s3);
            }
            int s = (s0 + s1) + (s2 + s3);
            s += __shfl_xor(s, 1);
            s += __shfl_xor(s, 2);
            if (v == 0 && live) Dsh[l][qi][it * 16 + grp] = (float)s * SCL;
            xo += 6;
            int cr = xo >= 10;
            xo -= cr ? 10 : 0;
            yo += 1 + cr;
        }
    }
    __syncthreads();

    // Bilinear combine + direct [B,324,HW] f32 write
    for (int o = tid; o < 324 * 4; o += 256) {
        int q = o & 3, ch = o >> 2;
        int lv = ch / 81;
        int o81 = ch - lv * 81;
        int xo = o81 / 9;                      // x-offset slow (reference quirk)
        int yo = o81 - xo * 9;                 // y-offset fast
        float wxv = Wxy[lv][q][0], wyv = Wxy[lv][q][1];
        const float* D = Dsh[lv][q];
        float v00 = D[yo * 10 + xo];
        float v01 = D[yo * 10 + xo + 1];
        float v10 = D[yo * 10 + xo + 10];
        float v11 = D[yo * 10 + xo + 11];
        float res = (1.f - wyv) * ((1.f - wxv) * v00 + wxv * v01)
                  +        wyv  * ((1.f - wxv) * v10 + wxv * v11);
        out0[((size_t)(b * 324 + ch)) * HW + hw0 + q] = res;
    }
}

extern "C" void kernel_launch(void* const* d_in, const int* in_sizes, int n_in,
                              void* d_out, int out_size, void* d_ws, size_t ws_size,
                              hipStream_t stream) {
    const float* fmap1  = (const float*)d_in[0];
    const float* fmap2  = (const float*)d_in[1];
    const float* coords = (const float*)d_in[2];
    const float* flow   = (const float*)d_in[3];
    const float* maskp  = (const float*)d_in[4];
    float* out = (float*)d_out;
    char* ws = (char*)d_ws;

    prep_kernel<<<TP_BLOCKS + CU_BLOCKS, 256, 0, stream>>>(
        fmap1, fmap2, flow, maskp, ws, out + OUT0_ELEMS);
    build_pools<<<(NP1 + NP2 + NP3) / 256, 256, 0, stream>>>(ws);
    corr_fused<<<B * HW / 4, 256, 0, stream>>>(coords, ws, out);
}

// Round 4
// 152.226 us; speedup vs baseline: 1.2346x; 1.0179x over previous
//
#include <hip/hip_runtime.h>
#include <math.h>

// Problem constants
constexpr int B = 2, C = 256, H = 56, W = 96;
constexpr int HW = H * W;
constexpr int RADIUS = 4;

// int8 quantization: scale 127/6 for both fmaps; dots rescaled at the end.
#define SQ 21.166666f                    // 127/6
constexpr float SCL = 36.0f / (127.0f * 127.0f * 16.0f);  // 1/(SQ^2 * sqrt(C))

// Workspace layout (byte offsets, all 16B-aligned)
constexpr size_t F1T_B = 0;                                   // i8 [B,HW,C]
constexpr size_t L0_B  = (size_t)B * HW * C;                  // i8 [B,HW,C]
constexpr size_t L1_B  = L0_B + (size_t)B * HW * C;           // i8 [B,28*48,C]
constexpr size_t L2_B  = L1_B + (size_t)B * 28 * 48 * C;      // i8 [B,14*24,C]
constexpr size_t L3_B  = L2_B + (size_t)B * 14 * 24 * C;      // i8 [B,7*12,C]
constexpr size_t OUT0_ELEMS = (size_t)B * 324 * HW;

static __device__ __forceinline__ int dot4acc(int a, int b, int c) {
#if __has_builtin(__builtin_amdgcn_sdot4)
    return __builtin_amdgcn_sdot4(a, b, c, false);
#else
    c += (int)(char)(a) * (int)(char)(b);
    c += (int)(char)(a >> 8) * (int)(char)(b >> 8);
    c += (int)(char)(a >> 16) * (int)(char)(b >> 16);
    c += (int)(char)(a >> 24) * (int)(char)(b >> 24);
    return c;
#endif
}

static __device__ __forceinline__ unsigned short pack_i8x2(float a, float b) {
    int ia = (int)rintf(a); ia = ia < -127 ? -127 : (ia > 127 ? 127 : ia);
    int ib = (int)rintf(b); ib = ib < -127 ? -127 : (ib > 127 ? 127 : ib);
    return (unsigned short)((ia & 0xFF) | ((ib & 0xFF) << 8));
}

// ---------------------------------------------------------------------------
// prep_kernel: fused {fp32->i8 channel-last transpose of fmap1/fmap2} and
// {convex upsample} (independent inputs).
constexpr int TP_BLOCKS = (HW / 32) * (C / 64) * 2 * B;   // 2688
constexpr int CU_BLOCKS = B * H * 8;                      // 896
__global__ __launch_bounds__(256) void prep_kernel(
    const float* __restrict__ fmap1, const float* __restrict__ fmap2,
    const float* __restrict__ flow, const float* __restrict__ mask,
    char* __restrict__ ws, float* __restrict__ out1) {
    __shared__ float smem[72 * 96 + 2 * 3 * 98];
    int bid = blockIdx.x;
    int tid = threadIdx.x;

    if (bid < TP_BLOCKS) {
        float (*tile)[33] = (float(*)[33])smem;   // 64 x 33 floats
        int zi = bid / 672;                       // 672 = 168*4
        int rem = bid % 672;
        int by = rem / 168, bx = rem % 168;
        int b = zi & 1, m = zi >> 1;              // m=0: fmap1, m=1: fmap2
        const float* src = m ? fmap2 : fmap1;
        unsigned short* dst = (unsigned short*)(ws + (m ? L0_B : F1T_B));
        int c0 = by * 64, q0 = bx * 32;
        int tx = tid & 31, ty = tid >> 5;
#pragma unroll
        for (int r = 0; r < 8; ++r) {
            int cl = ty + r * 8;
            tile[cl][tx] = src[((size_t)(b * C + c0 + cl)) * HW + q0 + tx];
        }
        __syncthreads();
#pragma unroll
        for (int r = 0; r < 4; ++r) {
            int pl = ty + r * 8;
            dst[((size_t)b * HW + q0 + pl) * 128 + (c0 >> 1) + tx] =
                pack_i8x2(tile[2 * tx][pl] * SQ, tile[2 * tx + 1][pl] * SQ);
        }
        return;
    }

    // ---- convex upsample ----
    float* msk = smem;               // 72*96
    float* fst = smem + 72 * 96;     // 2*3*98
    int cb = bid - TP_BLOCKS;
    int i = cb & 7;
    int r = cb >> 3;
    int h = r % H;
    int b = r / H;

    for (int idx = tid; idx < 72 * 96; idx += 256) {
        int row = idx / 96, wc = idx - row * 96;
        int k = row >> 3, j = row & 7;
        int gl = k * 64 + i * 8 + j;
        msk[idx] = mask[((size_t)(b * 576 + gl)) * HW + h * W + wc];
    }
    for (int idx = tid; idx < 588; idx += 256) {
        int ch = idx / 294;
        int rem2 = idx - ch * 294;
        int rr = rem2 / 98;
        int xw = rem2 - rr * 98;
        int hh = h + rr - 1, ww = xw - 1;
        float v = 0.f;
        if (hh >= 0 && hh < H && ww >= 0 && ww < W)
            v = 8.0f * flow[((size_t)(b * 2 + ch)) * HW + hh * W + ww];
        fst[idx] = v;
    }
    __syncthreads();

#pragma unroll
    for (int rr = 0; rr < 3; ++rr) {
        int col = tid + rr * 256;    // 0..767
        int w = col >> 3, j = col & 7;
        float m[9], mx = -1e30f;
#pragma unroll
        for (int k = 0; k < 9; ++k) {
            m[k] = msk[(k * 8 + j) * 96 + w];
            mx = fmaxf(mx, m[k]);
        }
        float sum = 0.f;
#pragma unroll
        for (int k = 0; k < 9; ++k) {
            m[k] = __expf(m[k] - mx);
            sum += m[k];
        }
        float inv = 1.0f / sum;
        float a0 = 0.f, a1 = 0.f;
#pragma unroll
        for (int k = 0; k < 9; ++k) {
            int ki = k / 3, kj = k - ki * 3;
            float wgt = m[k] * inv;
            a0 = fmaf(wgt, fst[0 * 294 + ki * 98 + w + kj], a0);
            a1 = fmaf(wgt, fst[1 * 294 + ki * 98 + w + kj], a1);
        }
        size_t row8 = (size_t)8 * h + i;
        out1[((size_t)(b * 2 + 0) * 448 + row8) * 768 + col] = a0;
        out1[((size_t)(b * 2 + 1) * 448 + row8) * 768 + col] = a1;
    }
}

// ---------------------------------------------------------------------------
// build_pools: pyramid levels 1..3 from i8 L0; one thread per channel PAIR.
constexpr int NP1 = B * 28 * 48 * C / 2;   // 344,064
constexpr int NP2 = B * 14 * 24 * C / 2;   //  86,016
constexpr int NP3 = B * 7 * 12 * C / 2;    //  21,504

template <int S>
static __device__ __forceinline__ void pool_accum(const unsigned short* src,
                                                  int& sx, int& sy) {
#pragma unroll
    for (int dy = 0; dy < S; ++dy)
#pragma unroll
        for (int dx = 0; dx < S; ++dx) {
            unsigned short v = src[(size_t)dy * (W * 128) + dx * 128];
            sx += (int)(char)(v & 0xFF);
            sy += (int)(char)(v >> 8);
        }
}

__global__ __launch_bounds__(256) void build_pools(char* __restrict__ ws) {
    const unsigned short* L0p = (const unsigned short*)(ws + L0_B);
    int t = blockIdx.x * 256 + threadIdx.x;
    int l, tl;
    if (t < NP1)             { l = 1; tl = t; }
    else if (t < NP1 + NP2)  { l = 2; tl = t - NP1; }
    else                     { l = 3; tl = t - NP1 - NP2; }
    int Wo = W >> l, Ho = H >> l, S = 1 << l;
    int c2 = tl & 127;
    int r = tl >> 7;
    int x = r % Wo; r /= Wo;
    int y = r % Ho;
    int b = r / Ho;
    const unsigned short* src =
        L0p + ((size_t)(b * H + y * S) * W + x * S) * 128 + c2;
    int sx = 0, sy = 0;
    if (l == 1)      pool_accum<2>(src, sx, sy);
    else if (l == 2) pool_accum<4>(src, sx, sy);
    else             pool_accum<8>(src, sx, sy);
    float inv = 1.0f / (S * S);
    unsigned short* dst = (unsigned short*)(ws + (l == 1 ? L1_B : (l == 2 ? L2_B : L3_B)));
    dst[tl] = pack_i8x2((float)sx * inv, (float)sy * inv);
}

// ---------------------------------------------------------------------------
// corr_fused: block = (one pyramid level, 16 consecutive queries).
// 4 waves x 4 queries each; 4 lanes per position (coalesced chunk order:
// instruction k = one 64-B line per position). UNCONDITIONAL clamped loads
// (OOB -> clamp address, cndmask result to 0) so the unrolled 7-iteration
// body software-pipelines. Epilogue writes full 64-B lines of out0
// (16 q x 4 B contiguous per channel).
constexpr int QB = 672;                    // B*HW/16 query-groups per level
__global__ __launch_bounds__(256, 6) void corr_fused(
    const float* __restrict__ coords, const char* __restrict__ ws,
    float* __restrict__ out0) {
    __shared__ float Dsh[16][101];   // stride 101: conflict-free reads
    __shared__ float Wxy[16][2];

    int tid = threadIdx.x;
    int wave = tid >> 6;
    int lane = tid & 63;
    int v = lane & 3;              // 16-B sub-chunk within each 64-B line
    int grp = lane >> 2;           // position index within iteration, 0..15

    int bid = blockIdx.x;
    int l = bid / QB;              // level: blocks grouped by level
    int qb = bid - l * QB;
    int g0 = qb * 16;              // 16 consecutive flat queries
    int b = g0 / HW;
    int hw0 = g0 - b * HW;

    int Hl = H >> l, Wl = W >> l;
    int Wlm1 = Wl - 1, Hlm1 = Hl - 1;
    size_t off = (l == 0 ? L0_B : (l == 1 ? L1_B : (l == 2 ? L2_B : L3_B)));
    const char* base8 = ws + off + (size_t)b * Hl * Wl * C;
    float scale = (l == 0 ? 1.0f : (l == 1 ? 0.5f : (l == 2 ? 0.25f : 0.125f)));

    // p = it*16 + grp; (xo,yo) = (p%10, p/10); advance p+=16: xo+=6 mod 10.
    int xo0 = grp < 10 ? grp : grp - 10;
    int yo0 = grp < 10 ? 0 : 1;

    const char* f1b = ws + F1T_B;

#pragma unroll 1
    for (int qi = 0; qi < 4; ++qi) {
        int wq = wave * 4 + qi;          // query slot 0..15
        int g = g0 + wq;
        // A chunks at k*64 + v*16 (match column partition; exact repartition)
        const char* ab = f1b + (size_t)g * C + (v << 4);
        int4 A0 = *(const int4*)(ab);
        int4 A1 = *(const int4*)(ab + 64);
        int4 A2 = *(const int4*)(ab + 128);
        int4 A3 = *(const int4*)(ab + 192);

        float cx = coords[(size_t)(b * 2 + 0) * HW + hw0 + wq];
        float cy = coords[(size_t)(b * 2 + 1) * HW + hw0 + wq];
        float fx = cx * scale, fy = cy * scale;
        float fxf = floorf(fx), fyf = floorf(fy);
        float wx = fx - fxf, wy = fy - fyf;
        int ix = (int)fxf, iy = (int)fyf;
        if (lane == 0) { Wxy[wq][0] = wx; Wxy[wq][1] = wy; }

        int xo = xo0, yo = yo0;
#pragma unroll
        for (int it = 0; it < 7; ++it) {
            int x = ix - RADIUS + xo;
            int y = iy - RADIUS + yo;
            bool valid = ((unsigned)x < (unsigned)Wl) & ((unsigned)y < (unsigned)Hl);
            int xc = min(max(x, 0), Wlm1);
            int yc = min(max(y, 0), Hlm1);
            const char* rp = base8 + ((yc * Wl + xc) << 8) + (v << 4);
            int4 c0 = *(const int4*)(rp);
            int4 c1 = *(const int4*)(rp + 64);
            int4 c2 = *(const int4*)(rp + 128);
            int4 c3 = *(const int4*)(rp + 192);
            int s0 = 0, s1 = 0, s2 = 0, s3 = 0;
            s0 = dot4acc(c0.x, A0.x, s0); s1 = dot4acc(c0.y, A0.y, s1);
            s2 = dot4acc(c0.z, A0.z, s2); s3 = dot4acc(c0.w, A0.w, s3);
            s0 = dot4acc(c1.x, A1.x, s0); s1 = dot4acc(c1.y, A1.y, s1);
            s2 = dot4acc(c1.z, A1.z, s2); s3 = dot4acc(c1.w, A1.w, s3);
            s0 = dot4acc(c2.x, A2.x, s0); s1 = dot4acc(c2.y, A2.y, s1);
            s2 = dot4acc(c2.z, A2.z, s2); s3 = dot4acc(c2.w, A2.w, s3);
            s0 = dot4acc(c3.x, A3.x, s0); s1 = dot4acc(c3.y, A3.y, s1);
            s2 = dot4acc(c3.z, A3.z, s2); s3 = dot4acc(c3.w, A3.w, s3);
            int s = (s0 + s1) + (s2 + s3);
            s = valid ? s : 0;
            s += __shfl_xor(s, 1);
            s += __shfl_xor(s, 2);
            bool live = (it < 6) | (grp < 4);      // p < 100
            if (v == 0 && live) Dsh[wq][it * 16 + grp] = (float)s * SCL;
            xo += 6;
            int cr = xo >= 10;
            xo -= cr ? 10 : 0;
            yo += 1 + cr;
        }
    }
    __syncthreads();

    // Bilinear combine + [B,324,HW] f32 write: 16 q x 4 B = full 64-B lines
    int chbase = l * 81;
    for (int o = tid; o < 81 * 16; o += 256) {
        int q = o & 15, ch = o >> 4;
        int xo = ch / 9;                       // x-offset slow (reference quirk)
        int yo = ch - xo * 9;                  // y-offset fast
        float wxv = Wxy[q][0], wyv = Wxy[q][1];
        const float* D = Dsh[q];
        float v00 = D[yo * 10 + xo];
        float v01 = D[yo * 10 + xo + 1];
        float v10 = D[yo * 10 + xo + 10];
        float v11 = D[yo * 10 + xo + 11];
        float res = (1.f - wyv) * ((1.f - wxv) * v00 + wxv * v01)
                  +        wyv  * ((1.f - wxv) * v10 + wxv * v11);
        out0[((size_t)(b * 324 + chbase + ch)) * HW + hw0 + q] = res;
    }
}

extern "C" void kernel_launch(void* const* d_in, const int* in_sizes, int n_in,
                              void* d_out, int out_size, void* d_ws, size_t ws_size,
                              hipStream_t stream) {
    const float* fmap1  = (const float*)d_in[0];
    const float* fmap2  = (const float*)d_in[1];
    const float* coords = (const float*)d_in[2];
    const float* flow   = (const float*)d_in[3];
    const float* maskp  = (const float*)d_in[4];
    float* out = (float*)d_out;
    char* ws = (char*)d_ws;

    prep_kernel<<<TP_BLOCKS + CU_BLOCKS, 256, 0, stream>>>(
        fmap1, fmap2, flow, maskp, ws, out + OUT0_ELEMS);
    build_pools<<<(NP1 + NP2 + NP3) / 256, 256, 0, stream>>>(ws);
    corr_fused<<<4 * QB, 256, 0, stream>>>(coords, ws, out);
}

// Round 5
// 152.155 us; speedup vs baseline: 1.2352x; 1.0005x over previous
//
#include <hip/hip_runtime.h>
#include <math.h>

// Problem constants
constexpr int B = 2, C = 256, H = 56, W = 96;
constexpr int HW = H * W;
constexpr int RADIUS = 4;

// int8 quantization: scale 127/6 for both fmaps; dots rescaled at the end.
#define SQ 21.166666f                    // 127/6
constexpr float SCL = 36.0f / (127.0f * 127.0f * 16.0f);  // 1/(SQ^2 * sqrt(C))

// Workspace layout (byte offsets, all 16B-aligned)
constexpr size_t F1T_B = 0;                                   // i8 [B,HW,C]
constexpr size_t L0_B  = (size_t)B * HW * C;                  // i8 [B,HW,C]
constexpr size_t L1_B  = L0_B + (size_t)B * HW * C;           // i8 [B,28*48,C]
constexpr size_t L2_B  = L1_B + (size_t)B * 28 * 48 * C;      // i8 [B,14*24,C]
constexpr size_t L3_B  = L2_B + (size_t)B * 14 * 24 * C;      // i8 [B,7*12,C]
constexpr size_t OUT0_ELEMS = (size_t)B * 324 * HW;

static __device__ __forceinline__ int dot4acc(int a, int b, int c) {
#if __has_builtin(__builtin_amdgcn_sdot4)
    return __builtin_amdgcn_sdot4(a, b, c, false);
#else
    c += (int)(char)(a) * (int)(char)(b);
    c += (int)(char)(a >> 8) * (int)(char)(b >> 8);
    c += (int)(char)(a >> 16) * (int)(char)(b >> 16);
    c += (int)(char)(a >> 24) * (int)(char)(b >> 24);
    return c;
#endif
}

static __device__ __forceinline__ unsigned short pack_i8x2(float a, float b) {
    int ia = (int)rintf(a); ia = ia < -127 ? -127 : (ia > 127 ? 127 : ia);
    int ib = (int)rintf(b); ib = ib < -127 ? -127 : (ib > 127 ? 127 : ib);
    return (unsigned short)((ia & 0xFF) | ((ib & 0xFF) << 8));
}

// ---------------------------------------------------------------------------
// prep_kernel: fused {fp32->i8 channel-last transpose of fmap1/fmap2} and
// {convex upsample} (independent inputs).
constexpr int TP_BLOCKS = (HW / 32) * (C / 64) * 2 * B;   // 2688
constexpr int CU_BLOCKS = B * H * 8;                      // 896
__global__ __launch_bounds__(256) void prep_kernel(
    const float* __restrict__ fmap1, const float* __restrict__ fmap2,
    const float* __restrict__ flow, const float* __restrict__ mask,
    char* __restrict__ ws, float* __restrict__ out1) {
    __shared__ float smem[72 * 96 + 2 * 3 * 98];
    int bid = blockIdx.x;
    int tid = threadIdx.x;

    if (bid < TP_BLOCKS) {
        float (*tile)[33] = (float(*)[33])smem;   // 64 x 33 floats
        int zi = bid / 672;                       // 672 = 168*4
        int rem = bid % 672;
        int by = rem / 168, bx = rem % 168;
        int b = zi & 1, m = zi >> 1;              // m=0: fmap1, m=1: fmap2
        const float* src = m ? fmap2 : fmap1;
        unsigned short* dst = (unsigned short*)(ws + (m ? L0_B : F1T_B));
        int c0 = by * 64, q0 = bx * 32;
        int tx = tid & 31, ty = tid >> 5;
#pragma unroll
        for (int r = 0; r < 8; ++r) {
            int cl = ty + r * 8;
            tile[cl][tx] = src[((size_t)(b * C + c0 + cl)) * HW + q0 + tx];
        }
        __syncthreads();
#pragma unroll
        for (int r = 0; r < 4; ++r) {
            int pl = ty + r * 8;
            dst[((size_t)b * HW + q0 + pl) * 128 + (c0 >> 1) + tx] =
                pack_i8x2(tile[2 * tx][pl] * SQ, tile[2 * tx + 1][pl] * SQ);
        }
        return;
    }

    // ---- convex upsample ----
    float* msk = smem;               // 72*96
    float* fst = smem + 72 * 96;     // 2*3*98
    int cb = bid - TP_BLOCKS;
    int i = cb & 7;
    int r = cb >> 3;
    int h = r % H;
    int b = r / H;

    for (int idx = tid; idx < 72 * 96; idx += 256) {
        int row = idx / 96, wc = idx - row * 96;
        int k = row >> 3, j = row & 7;
        int gl = k * 64 + i * 8 + j;
        msk[idx] = mask[((size_t)(b * 576 + gl)) * HW + h * W + wc];
    }
    for (int idx = tid; idx < 588; idx += 256) {
        int ch = idx / 294;
        int rem2 = idx - ch * 294;
        int rr = rem2 / 98;
        int xw = rem2 - rr * 98;
        int hh = h + rr - 1, ww = xw - 1;
        float v = 0.f;
        if (hh >= 0 && hh < H && ww >= 0 && ww < W)
            v = 8.0f * flow[((size_t)(b * 2 + ch)) * HW + hh * W + ww];
        fst[idx] = v;
    }
    __syncthreads();

#pragma unroll
    for (int rr = 0; rr < 3; ++rr) {
        int col = tid + rr * 256;    // 0..767
        int w = col >> 3, j = col & 7;
        float m[9], mx = -1e30f;
#pragma unroll
        for (int k = 0; k < 9; ++k) {
            m[k] = msk[(k * 8 + j) * 96 + w];
            mx = fmaxf(mx, m[k]);
        }
        float sum = 0.f;
#pragma unroll
        for (int k = 0; k < 9; ++k) {
            m[k] = __expf(m[k] - mx);
            sum += m[k];
        }
        float inv = 1.0f / sum;
        float a0 = 0.f, a1 = 0.f;
#pragma unroll
        for (int k = 0; k < 9; ++k) {
            int ki = k / 3, kj = k - ki * 3;
            float wgt = m[k] * inv;
            a0 = fmaf(wgt, fst[0 * 294 + ki * 98 + w + kj], a0);
            a1 = fmaf(wgt, fst[1 * 294 + ki * 98 + w + kj], a1);
        }
        size_t row8 = (size_t)8 * h + i;
        out1[((size_t)(b * 2 + 0) * 448 + row8) * 768 + col] = a0;
        out1[((size_t)(b * 2 + 1) * 448 + row8) * 768 + col] = a1;
    }
}

// ---------------------------------------------------------------------------
// build_pools: pyramid levels 1..3 from i8 L0; one thread per channel PAIR.
constexpr int NP1 = B * 28 * 48 * C / 2;   // 344,064
constexpr int NP2 = B * 14 * 24 * C / 2;   //  86,016
constexpr int NP3 = B * 7 * 12 * C / 2;    //  21,504

template <int S>
static __device__ __forceinline__ void pool_accum(const unsigned short* src,
                                                  int& sx, int& sy) {
#pragma unroll
    for (int dy = 0; dy < S; ++dy)
#pragma unroll
        for (int dx = 0; dx < S; ++dx) {
            unsigned short v = src[(size_t)dy * (W * 128) + dx * 128];
            sx += (int)(char)(v & 0xFF);
            sy += (int)(char)(v >> 8);
        }
}

__global__ __launch_bounds__(256) void build_pools(char* __restrict__ ws) {
    const unsigned short* L0p = (const unsigned short*)(ws + L0_B);
    int t = blockIdx.x * 256 + threadIdx.x;
    int l, tl;
    if (t < NP1)             { l = 1; tl = t; }
    else if (t < NP1 + NP2)  { l = 2; tl = t - NP1; }
    else                     { l = 3; tl = t - NP1 - NP2; }
    int Wo = W >> l, Ho = H >> l, S = 1 << l;
    int c2 = tl & 127;
    int r = tl >> 7;
    int x = r % Wo; r /= Wo;
    int y = r % Ho;
    int b = r / Ho;
    const unsigned short* src =
        L0p + ((size_t)(b * H + y * S) * W + x * S) * 128 + c2;
    int sx = 0, sy = 0;
    if (l == 1)      pool_accum<2>(src, sx, sy);
    else if (l == 2) pool_accum<4>(src, sx, sy);
    else             pool_accum<8>(src, sx, sy);
    float inv = 1.0f / (S * S);
    unsigned short* dst = (unsigned short*)(ws + (l == 1 ? L1_B : (l == 2 ? L2_B : L3_B)));
    dst[tl] = pack_i8x2((float)sx * inv, (float)sy * inv);
}

// ---------------------------------------------------------------------------
// corr_fused: block = (one pyramid level, 16 consecutive queries).
// 4 waves x 4 queries each; 4 lanes per position, coalesced chunk order
// (instruction k = one 64-B line per position). Per query: precompute all 7
// clamped offsets + validity mask, then EXPLICIT 2-deep double-buffered
// pipeline (issue iter it+1's 4 loads before iter it's 16 dots) so one full
// load batch is always in flight. launch_bounds(256,4) gives the VGPR budget.
constexpr int QB = 672;                    // B*HW/16 query-groups per level
__global__ __launch_bounds__(256, 4) void corr_fused(
    const float* __restrict__ coords, const char* __restrict__ ws,
    float* __restrict__ out0) {
    __shared__ float Dsh[16][101];   // stride 101: conflict-free reads
    __shared__ float Wxy[16][2];

    int tid = threadIdx.x;
    int wave = tid >> 6;
    int lane = tid & 63;
    int v = lane & 3;              // 16-B sub-chunk within each 64-B line
    int grp = lane >> 2;           // position index within iteration, 0..15

    int bid = blockIdx.x;
    int l = bid / QB;              // level: blocks grouped by level
    int qb = bid - l * QB;
    int g0 = qb * 16;              // 16 consecutive flat queries
    int b = g0 / HW;
    int hw0 = g0 - b * HW;

    int Hl = H >> l, Wl = W >> l;
    int Wlm1 = Wl - 1, Hlm1 = Hl - 1;
    size_t off = (l == 0 ? L0_B : (l == 1 ? L1_B : (l == 2 ? L2_B : L3_B)));
    const char* base8 = ws + off + (size_t)b * Hl * Wl * C;
    float scale = (l == 0 ? 1.0f : (l == 1 ? 0.5f : (l == 2 ? 0.25f : 0.125f)));

    // p = it*16 + grp; (xo,yo) = (p%10, p/10); advance p+=16: xo+=6 mod 10.
    int xo0 = grp < 10 ? grp : grp - 10;
    int yo0 = grp < 10 ? 0 : 1;

    const char* f1b = ws + F1T_B;

#pragma unroll 1
    for (int qi = 0; qi < 4; ++qi) {
        int wq = wave * 4 + qi;          // query slot 0..15
        int g = g0 + wq;
        // A chunks at k*64 + v*16 (match column partition; exact repartition)
        const char* ab = f1b + (size_t)g * C + (v << 4);
        int4 A0 = *(const int4*)(ab);
        int4 A1 = *(const int4*)(ab + 64);
        int4 A2 = *(const int4*)(ab + 128);
        int4 A3 = *(const int4*)(ab + 192);

        float cx = coords[(size_t)(b * 2 + 0) * HW + hw0 + wq];
        float cy = coords[(size_t)(b * 2 + 1) * HW + hw0 + wq];
        float fx = cx * scale, fy = cy * scale;
        float fxf = floorf(fx), fyf = floorf(fy);
        float wx = fx - fxf, wy = fy - fyf;
        int ix = (int)fxf, iy = (int)fyf;
        if (lane == 0) { Wxy[wq][0] = wx; Wxy[wq][1] = wy; }

        // Precompute the 7 clamped byte offsets + validity bits (pure VALU;
        // also covers the A-load latency above).
        int offv[7];
        unsigned vmask = 0;
        {
            int xo = xo0, yo = yo0;
#pragma unroll
            for (int it = 0; it < 7; ++it) {
                int x = ix - RADIUS + xo;
                int y = iy - RADIUS + yo;
                if (((unsigned)x < (unsigned)Wl) & ((unsigned)y < (unsigned)Hl))
                    vmask |= 1u << it;
                int xc = min(max(x, 0), Wlm1);
                int yc = min(max(y, 0), Hlm1);
                offv[it] = ((yc * Wl + xc) << 8) + (v << 4);
                xo += 6;
                int cr = xo >= 10;
                xo -= cr ? 10 : 0;
                yo += 1 + cr;
            }
        }

        // 2-deep pipelined dot loop
        int4 c0 = *(const int4*)(base8 + offv[0]);
        int4 c1 = *(const int4*)(base8 + offv[0] + 64);
        int4 c2 = *(const int4*)(base8 + offv[0] + 128);
        int4 c3 = *(const int4*)(base8 + offv[0] + 192);
#pragma unroll
        for (int it = 0; it < 7; ++it) {
            int4 n0, n1, n2, n3;
            if (it < 6) {
                n0 = *(const int4*)(base8 + offv[it + 1]);
                n1 = *(const int4*)(base8 + offv[it + 1] + 64);
                n2 = *(const int4*)(base8 + offv[it + 1] + 128);
                n3 = *(const int4*)(base8 + offv[it + 1] + 192);
            }
            int s0 = 0, s1 = 0, s2 = 0, s3 = 0;
            s0 = dot4acc(c0.x, A0.x, s0); s1 = dot4acc(c0.y, A0.y, s1);
            s2 = dot4acc(c0.z, A0.z, s2); s3 = dot4acc(c0.w, A0.w, s3);
            s0 = dot4acc(c1.x, A1.x, s0); s1 = dot4acc(c1.y, A1.y, s1);
            s2 = dot4acc(c1.z, A1.z, s2); s3 = dot4acc(c1.w, A1.w, s3);
            s0 = dot4acc(c2.x, A2.x, s0); s1 = dot4acc(c2.y, A2.y, s1);
            s2 = dot4acc(c2.z, A2.z, s2); s3 = dot4acc(c2.w, A2.w, s3);
            s0 = dot4acc(c3.x, A3.x, s0); s1 = dot4acc(c3.y, A3.y, s1);
            s2 = dot4acc(c3.z, A3.z, s2); s3 = dot4acc(c3.w, A3.w, s3);
            int s = (s0 + s1) + (s2 + s3);
            s = ((vmask >> it) & 1) ? s : 0;
            s += __shfl_xor(s, 1);
            s += __shfl_xor(s, 2);
            bool live = (it < 6) | (grp < 4);      // p < 100
            if (v == 0 && live) Dsh[wq][it * 16 + grp] = (float)s * SCL;
            if (it < 6) { c0 = n0; c1 = n1; c2 = n2; c3 = n3; }
        }
    }
    __syncthreads();

    // Bilinear combine + [B,324,HW] f32 write: 16 q x 4 B = full 64-B lines
    int chbase = l * 81;
    for (int o = tid; o < 81 * 16; o += 256) {
        int q = o & 15, ch = o >> 4;
        int xo = ch / 9;                       // x-offset slow (reference quirk)
        int yo = ch - xo * 9;                  // y-offset fast
        float wxv = Wxy[q][0], wyv = Wxy[q][1];
        const float* D = Dsh[q];
        float v00 = D[yo * 10 + xo];
        float v01 = D[yo * 10 + xo + 1];
        float v10 = D[yo * 10 + xo + 10];
        float v11 = D[yo * 10 + xo + 11];
        float res = (1.f - wyv) * ((1.f - wxv) * v00 + wxv * v01)
                  +        wyv  * ((1.f - wxv) * v10 + wxv * v11);
        out0[((size_t)(b * 324 + chbase + ch)) * HW + hw0 + q] = res;
    }
}

extern "C" void kernel_launch(void* const* d_in, const int* in_sizes, int n_in,
                              void* d_out, int out_size, void* d_ws, size_t ws_size,
                              hipStream_t stream) {
    const float* fmap1  = (const float*)d_in[0];
    const float* fmap2  = (const float*)d_in[1];
    const float* coords = (const float*)d_in[2];
    const float* flow   = (const float*)d_in[3];
    const float* maskp  = (const float*)d_in[4];
    float* out = (float*)d_out;
    char* ws = (char*)d_ws;

    prep_kernel<<<TP_BLOCKS + CU_BLOCKS, 256, 0, stream>>>(
        fmap1, fmap2, flow, maskp, ws, out + OUT0_ELEMS);
    build_pools<<<(NP1 + NP2 + NP3) / 256, 256, 0, stream>>>(ws);
    corr_fused<<<4 * QB, 256, 0, stream>>>(coords, ws, out);
}